// Round 11
// baseline (241.379 us; speedup 1.0000x reference)
//
#include <hip/hip_runtime.h>
#include <math.h>
#include <type_traits>

#define DEV __device__ __forceinline__

DEV float gelu_exact(float x) {
    return 0.5f * x * (1.0f + erff(x * 0.70710678118654752f));
}

// ---------------- K1: adjacency -> CSR neighbor lists ----------------
// MEASUREMENT: body repeated 'reps' times (idempotent; true time = dur/reps).
__global__ __launch_bounds__(512)
void mask_kernel(const float* __restrict__ emb,
                 unsigned short* __restrict__ nbr,
                 int* __restrict__ deg, int reps) {
    __shared__ unsigned wcnt[8];
    const int i = blockIdx.x;
    const int j = threadIdx.x;
#pragma unroll 1
    for (int rep = 0; rep < reps; ++rep) {
        float ei[8], ej[8];
        float si = 0.f, sj = 0.f;
#pragma unroll
        for (int e = 0; e < 8; ++e) { ei[e] = emb[i * 8 + e]; si += ei[e] * ei[e]; }
        const int jj = (j < 500) ? j : 0;
#pragma unroll
        for (int e = 0; e < 8; ++e) { ej[e] = emb[jj * 8 + e]; sj += ej[e] * ej[e]; }
        const float ri = 1.0f / sqrtf(si);
        const float rj = 1.0f / sqrtf(sj);
        float dot = 0.f;
#pragma unroll
        for (int e = 0; e < 8; ++e) dot += (ei[e] * ri) * (ej[e] * rj);
        const bool pred = (j < 500) && (dot > 0.5f);
        const unsigned long long m = __ballot(pred);

        const int wave = j >> 6, lane = j & 63;
        if (lane == 0) wcnt[wave] = (unsigned)__popcll(m);
        __syncthreads();
        unsigned off = 0;
        for (int w = 0; w < wave; ++w) off += wcnt[w];
        if (pred) {
            const unsigned pos = off + (unsigned)__popcll(m & ((1ull << lane) - 1ull));
            if (pos < 128) nbr[i * 128 + pos] = (unsigned short)j;
        }
        if (j == 0) {
            unsigned t = 0;
            for (int w = 0; w < 8; ++w) t += wcnt[w];
            deg[i] = (int)(t > 128u ? 128u : t);
        }
        __syncthreads();  // wcnt reuse hazard across reps
    }
}

// ---------------- K2/K3: per-layer GAT (math identical to R8) ----------------
template <int C, int OUTS, bool PROJ, bool GELU_OUT>
__global__ __launch_bounds__(512)
void gat_kernel(const float* __restrict__ in,
                const float* __restrict__ pw,
                const float* __restrict__ pb,
                const float* __restrict__ W,
                const float* __restrict__ asrc,
                const float* __restrict__ adst,
                const float* __restrict__ bias,
                const unsigned short* __restrict__ nbr,
                const int* __restrict__ deg,
                float* __restrict__ out, int reps) {
    using Vec = std::conditional_t<C == 2, float2, float4>;
    const int b = blockIdx.x >> 2;
    const int head = blockIdx.x & 3;
    const int tid = threadIdx.x;
    __shared__ float xh[500 * 9];
    __shared__ Vec h1[500];
    __shared__ float ssrc[500];
    __shared__ float sdst[500];

#pragma unroll 1
    for (int rep = 0; rep < reps; ++rep) {
        if (tid < 500) {
            if constexpr (PROJ) {
                const float* xr = in + ((size_t)b * 500 + tid) * 3;
                const float x0 = xr[0], x1 = xr[1], x2 = xr[2];
#pragma unroll
                for (int e = 0; e < 8; ++e)
                    xh[tid * 9 + e] = x0 * pw[e] + x1 * pw[8 + e] + x2 * pw[16 + e] + pb[e];
            } else {
                const float4* xr = (const float4*)(in + ((size_t)b * 500 + tid) * 8);
                const float4 v0 = xr[0], v1 = xr[1];
                xh[tid * 9 + 0] = v0.x; xh[tid * 9 + 1] = v0.y;
                xh[tid * 9 + 2] = v0.z; xh[tid * 9 + 3] = v0.w;
                xh[tid * 9 + 4] = v1.x; xh[tid * 9 + 5] = v1.y;
                xh[tid * 9 + 6] = v1.z; xh[tid * 9 + 7] = v1.w;
            }
        }
        __syncthreads();

        if (tid < 500) {
            float xv[8];
#pragma unroll
            for (int e = 0; e < 8; ++e) xv[e] = xh[tid * 9 + e];
            float acc[C];
#pragma unroll
            for (int c = 0; c < C; ++c) acc[c] = 0.f;
#pragma unroll
            for (int e = 0; e < 8; ++e) {
                const float xe = xv[e];
#pragma unroll
                for (int c = 0; c < C; ++c) acc[c] += xe * W[(e * 4 + head) * C + c];
            }
            float ss = 0.f, sd = 0.f;
#pragma unroll
            for (int c = 0; c < C; ++c) {
                ss += acc[c] * asrc[head * C + c];
                sd += acc[c] * adst[head * C + c];
            }
            Vec hv;
            if constexpr (C == 2) { hv.x = acc[0]; hv.y = acc[1]; }
            else { hv.x = acc[0]; hv.y = acc[1]; hv.z = acc[2]; hv.w = acc[3]; }
            h1[tid] = hv;
            ssrc[tid] = ss;
            sdst[tid] = sd;
        }
        __syncthreads();

        if (tid < 500) {
            const int i = tid;
            const float dd = sdst[i];
            const int dg = deg[i];
            const unsigned short* nb = nbr + i * 128;
            float num[C];
#pragma unroll
            for (int c = 0; c < C; ++c) num[c] = 0.f;
            float den = 0.f;
            int k = 0;
            for (; k + 4 <= dg; k += 4) {
                const ushort4 j4 = *(const ushort4*)(nb + k);
                float e0 = dd + ssrc[j4.x]; e0 = (e0 > 0.f) ? e0 : 0.2f * e0;
                float e1 = dd + ssrc[j4.y]; e1 = (e1 > 0.f) ? e1 : 0.2f * e1;
                float e2 = dd + ssrc[j4.z]; e2 = (e2 > 0.f) ? e2 : 0.2f * e2;
                float e3 = dd + ssrc[j4.w]; e3 = (e3 > 0.f) ? e3 : 0.2f * e3;
                const float w0 = __expf(e0), w1 = __expf(e1);
                const float w2 = __expf(e2), w3 = __expf(e3);
                const Vec ha = h1[j4.x], hb = h1[j4.y], hc = h1[j4.z], hd = h1[j4.w];
                den += (w0 + w1) + (w2 + w3);
                if constexpr (C == 2) {
                    num[0] += (w0 * ha.x + w1 * hb.x) + (w2 * hc.x + w3 * hd.x);
                    num[1] += (w0 * ha.y + w1 * hb.y) + (w2 * hc.y + w3 * hd.y);
                } else {
                    num[0] += (w0 * ha.x + w1 * hb.x) + (w2 * hc.x + w3 * hd.x);
                    num[1] += (w0 * ha.y + w1 * hb.y) + (w2 * hc.y + w3 * hd.y);
                    num[2] += (w0 * ha.z + w1 * hb.z) + (w2 * hc.z + w3 * hd.z);
                    num[3] += (w0 * ha.w + w1 * hb.w) + (w2 * hc.w + w3 * hd.w);
                }
            }
            for (; k < dg; ++k) {
                const int j = nb[k];
                float e = dd + ssrc[j];
                e = (e > 0.f) ? e : 0.2f * e;
                const float w = __expf(e);
                den += w;
                const Vec hj = h1[j];
                if constexpr (C == 2) { num[0] += w * hj.x; num[1] += w * hj.y; }
                else { num[0] += w * hj.x; num[1] += w * hj.y;
                       num[2] += w * hj.z; num[3] += w * hj.w; }
            }
            const float inv = 1.0f / den;
            float* orow = out + ((size_t)b * 500 + i) * OUTS + head * C;
#pragma unroll
            for (int c = 0; c < C; ++c) {
                float v = num[c] * inv + bias[head * C + c];
                if constexpr (GELU_OUT) v = gelu_exact(v);
                orow[c] = v;
            }
        }
        __syncthreads();  // h1/ssrc reuse hazard across reps
    }
}

// ---------------- K4: transformer (math identical to R9) ----------------
__global__ __launch_bounds__(64)
void transformer_kernel(const float* __restrict__ tin,  // [2000,24,16]
                        const float* __restrict__ wq, const float* __restrict__ bq,
                        const float* __restrict__ wk, const float* __restrict__ bk,
                        const float* __restrict__ wv, const float* __restrict__ bv,
                        const float* __restrict__ wo, const float* __restrict__ bo,
                        const float* __restrict__ ln1g, const float* __restrict__ ln1b,
                        const float* __restrict__ ln2g, const float* __restrict__ ln2b,
                        const float* __restrict__ fw1, const float* __restrict__ fb1,
                        const float* __restrict__ fw2, const float* __restrict__ fb2,
                        const float* __restrict__ rw1, const float* __restrict__ rb1,
                        const float* __restrict__ rw2, const float* __restrict__ rb2,
                        float* __restrict__ outp, int reps) {
    const int r = blockIdx.x;
    const int lane = threadIdx.x;
    const int d = lane & 15;
    const int srow = lane >> 4;
    const int f = lane & 31;
    const int s2 = lane >> 5;
    __shared__ float t0[24][16], qs[24][16], ks[24][16], vs[24][16];
    __shared__ float os[24][16], t1[24][16], hid[24][32], pooled[16];

#pragma unroll 1
    for (int rep = 0; rep < reps; ++rep) {
        const float4* row4 = (const float4*)(tin + (size_t)r * 384);
        float4* t04 = (float4*)&t0[0][0];
#pragma unroll 1
        for (int idx = lane; idx < 96; idx += 64) t04[idx] = row4[idx];
        float wqc[16], wkc[16], wvc[16];
#pragma unroll
        for (int e = 0; e < 16; ++e) {
            wqc[e] = wq[e * 16 + d];
            wkc[e] = wk[e * 16 + d];
            wvc[e] = wv[e * 16 + d];
        }
        const float bqv = bq[d], bkv = bk[d], bvv = bv[d];
        __syncthreads();

#pragma unroll 1
        for (int it = 0; it < 6; ++it) {
            const int s = it * 4 + srow;
            const float4 r0 = *(const float4*)&t0[s][0];
            const float4 r1 = *(const float4*)&t0[s][4];
            const float4 r2 = *(const float4*)&t0[s][8];
            const float4 r3 = *(const float4*)&t0[s][12];
            const float te[16] = {r0.x, r0.y, r0.z, r0.w, r1.x, r1.y, r1.z, r1.w,
                                  r2.x, r2.y, r2.z, r2.w, r3.x, r3.y, r3.z, r3.w};
            float aq = bqv, ak = bkv, av = bvv;
#pragma unroll
            for (int e = 0; e < 16; ++e) {
                aq += te[e] * wqc[e];
                ak += te[e] * wkc[e];
                av += te[e] * wvc[e];
            }
            qs[s][d] = aq; ks[s][d] = ak; vs[s][d] = av;
        }
        __syncthreads();

        if (lane < 48) {
            const int h = lane / 24, s = lane % 24;
            const float4 q0 = *(const float4*)&qs[s][h * 8];
            const float4 q1 = *(const float4*)&qs[s][h * 8 + 4];
            float sc[24];
            float mx = -1e30f;
#pragma unroll
            for (int t = 0; t < 24; ++t) {
                const float4 k0 = *(const float4*)&ks[t][h * 8];
                const float4 k1 = *(const float4*)&ks[t][h * 8 + 4];
                float a = q0.x * k0.x + q0.y * k0.y + q0.z * k0.z + q0.w * k0.w +
                          q1.x * k1.x + q1.y * k1.y + q1.z * k1.z + q1.w * k1.w;
                a *= 0.35355339059327373f;
                sc[t] = a;
                mx = fmaxf(mx, a);
            }
            float sum = 0.f;
#pragma unroll
            for (int t = 0; t < 24; ++t) { sc[t] = __expf(sc[t] - mx); sum += sc[t]; }
            const float inv = 1.0f / sum;
            float o0x = 0.f, o0y = 0.f, o0z = 0.f, o0w = 0.f;
            float o1x = 0.f, o1y = 0.f, o1z = 0.f, o1w = 0.f;
#pragma unroll
            for (int t = 0; t < 24; ++t) {
                const float4 v0 = *(const float4*)&vs[t][h * 8];
                const float4 v1 = *(const float4*)&vs[t][h * 8 + 4];
                const float w = sc[t];
                o0x += w * v0.x; o0y += w * v0.y; o0z += w * v0.z; o0w += w * v0.w;
                o1x += w * v1.x; o1y += w * v1.y; o1z += w * v1.z; o1w += w * v1.w;
            }
            float4 ov0 = {o0x * inv, o0y * inv, o0z * inv, o0w * inv};
            float4 ov1 = {o1x * inv, o1y * inv, o1z * inv, o1w * inv};
            *(float4*)&os[s][h * 8] = ov0;
            *(float4*)&os[s][h * 8 + 4] = ov1;
        }
        float woc[16];
#pragma unroll
        for (int hd = 0; hd < 16; ++hd) woc[hd] = wo[hd * 16 + d];
        const float bov = bo[d];
        const float g1v = ln1g[d], be1v = ln1b[d];
        __syncthreads();

#pragma unroll 1
        for (int it = 0; it < 6; ++it) {
            const int s = it * 4 + srow;
            const float4 r0 = *(const float4*)&os[s][0];
            const float4 r1 = *(const float4*)&os[s][4];
            const float4 r2 = *(const float4*)&os[s][8];
            const float4 r3 = *(const float4*)&os[s][12];
            const float oe[16] = {r0.x, r0.y, r0.z, r0.w, r1.x, r1.y, r1.z, r1.w,
                                  r2.x, r2.y, r2.z, r2.w, r3.x, r3.y, r3.z, r3.w};
            float a = bov;
#pragma unroll
            for (int hd = 0; hd < 16; ++hd) a += oe[hd] * woc[hd];
            const float xv = t0[s][d] + a;
            float s1 = xv, sq = xv * xv;
            s1 += __shfl_xor(s1, 1); sq += __shfl_xor(sq, 1);
            s1 += __shfl_xor(s1, 2); sq += __shfl_xor(sq, 2);
            s1 += __shfl_xor(s1, 4); sq += __shfl_xor(sq, 4);
            s1 += __shfl_xor(s1, 8); sq += __shfl_xor(sq, 8);
            const float mean = s1 * 0.0625f;
            const float var = fmaxf(sq * 0.0625f - mean * mean, 0.f);
            t1[s][d] = (xv - mean) * rsqrtf(var + 1e-3f) * g1v + be1v;
        }
        float f1c[16];
#pragma unroll
        for (int e = 0; e < 16; ++e) f1c[e] = fw1[e * 32 + f];
        const float fb1v = fb1[f];
        __syncthreads();

#pragma unroll 1
        for (int it = 0; it < 12; ++it) {
            const int s = it * 2 + s2;
            const float4 r0 = *(const float4*)&t1[s][0];
            const float4 r1 = *(const float4*)&t1[s][4];
            const float4 r2 = *(const float4*)&t1[s][8];
            const float4 r3 = *(const float4*)&t1[s][12];
            const float te[16] = {r0.x, r0.y, r0.z, r0.w, r1.x, r1.y, r1.z, r1.w,
                                  r2.x, r2.y, r2.z, r2.w, r3.x, r3.y, r3.z, r3.w};
            float a = fb1v;
#pragma unroll
            for (int e = 0; e < 16; ++e) a += te[e] * f1c[e];
            hid[s][f] = gelu_exact(a);
        }
        float f2c[32];
#pragma unroll
        for (int ff = 0; ff < 32; ++ff) f2c[ff] = fw2[ff * 16 + d];
        const float fb2v = fb2[d];
        const float g2v = ln2g[d], be2v = ln2b[d];
        __syncthreads();

        float pacc = 0.f;
#pragma unroll 1
        for (int it = 0; it < 6; ++it) {
            const int s = it * 4 + srow;
            float he[32];
#pragma unroll
            for (int q8 = 0; q8 < 8; ++q8) {
                const float4 rv = *(const float4*)&hid[s][q8 * 4];
                he[q8 * 4 + 0] = rv.x; he[q8 * 4 + 1] = rv.y;
                he[q8 * 4 + 2] = rv.z; he[q8 * 4 + 3] = rv.w;
            }
            float a = fb2v;
#pragma unroll
            for (int ff = 0; ff < 32; ++ff) a += he[ff] * f2c[ff];
            const float xv = t1[s][d] + a;
            float s1 = xv, sq = xv * xv;
            s1 += __shfl_xor(s1, 1); sq += __shfl_xor(sq, 1);
            s1 += __shfl_xor(s1, 2); sq += __shfl_xor(sq, 2);
            s1 += __shfl_xor(s1, 4); sq += __shfl_xor(sq, 4);
            s1 += __shfl_xor(s1, 8); sq += __shfl_xor(sq, 8);
            const float mean = s1 * 0.0625f;
            const float var = fmaxf(sq * 0.0625f - mean * mean, 0.f);
            pacc += (xv - mean) * rsqrtf(var + 1e-3f) * g2v + be2v;
        }
        pacc += __shfl_xor(pacc, 16);
        pacc += __shfl_xor(pacc, 32);
        if (lane < 16) pooled[lane] = pacc * (1.0f / 24.0f);
        __syncthreads();

        float partial = 0.f;
        if (lane < 16) {
            float a = rb1[lane];
#pragma unroll
            for (int e = 0; e < 16; ++e) a += pooled[e] * rw1[e * 16 + lane];
            partial = gelu_exact(a) * rw2[lane];
        }
        partial += __shfl_xor(partial, 8);
        partial += __shfl_xor(partial, 4);
        partial += __shfl_xor(partial, 2);
        partial += __shfl_xor(partial, 1);
        if (lane == 0) outp[r] = partial + rb2[0];
        __syncthreads();  // pooled reuse hazard across reps
    }
}

extern "C" void kernel_launch(void* const* d_in, const int* in_sizes, int n_in,
                              void* d_out, int out_size, void* d_ws, size_t ws_size,
                              hipStream_t stream) {
    const float* x      = (const float*)d_in[0];
    const float* emb    = (const float*)d_in[1];
    const float* proj_w = (const float*)d_in[2];
    const float* proj_b = (const float*)d_in[3];
    const float* g1_w   = (const float*)d_in[4];
    const float* g1_as  = (const float*)d_in[5];
    const float* g1_ad  = (const float*)d_in[6];
    const float* g1_b   = (const float*)d_in[7];
    const float* g2_w   = (const float*)d_in[8];
    const float* g2_as  = (const float*)d_in[9];
    const float* g2_ad  = (const float*)d_in[10];
    const float* g2_b   = (const float*)d_in[11];
    const float* wq = (const float*)d_in[12];
    const float* bq = (const float*)d_in[13];
    const float* wk = (const float*)d_in[14];
    const float* bk = (const float*)d_in[15];
    const float* wv = (const float*)d_in[16];
    const float* bv = (const float*)d_in[17];
    const float* wo = (const float*)d_in[18];
    const float* bo = (const float*)d_in[19];
    const float* ln1g = (const float*)d_in[20];
    const float* ln1b = (const float*)d_in[21];
    const float* ln2g = (const float*)d_in[22];
    const float* ln2b = (const float*)d_in[23];
    const float* fw1 = (const float*)d_in[24];
    const float* fb1 = (const float*)d_in[25];
    const float* fw2 = (const float*)d_in[26];
    const float* fb2 = (const float*)d_in[27];
    const float* rw1 = (const float*)d_in[28];
    const float* rb1 = (const float*)d_in[29];
    const float* rw2 = (const float*)d_in[30];
    const float* rb2 = (const float*)d_in[31];

    unsigned short* nbr = (unsigned short*)d_ws;                  // 128,000 B (pad 131072)
    int* deg   = (int*)((char*)d_ws + 131072);                    // 2,000 B (pad 4096)
    float* h_g1  = (float*)((char*)d_ws + 135168);                // 1,536,000 B
    float* t_buf = (float*)((char*)d_ws + 135168 + 1536000);      // 3,072,000 B

    // MEASUREMENT ROUND: rep counts chosen to push each kernel above the
    // ~40us fill-dispatch floor in the top-5 profile. True time = dur/reps.
    mask_kernel<<<500, 512, 0, stream>>>(emb, nbr, deg, 24);
    gat_kernel<2, 8, true, true><<<384, 512, 0, stream>>>(
        x, proj_w, proj_b, g1_w, g1_as, g1_ad, g1_b, nbr, deg, h_g1, 8);
    gat_kernel<4, 16, false, false><<<384, 512, 0, stream>>>(
        h_g1, nullptr, nullptr, g2_w, g2_as, g2_ad, g2_b, nbr, deg, t_buf, 8);
    transformer_kernel<<<2000, 64, 0, stream>>>(
        t_buf, wq, bq, wk, bk, wv, bv, wo, bo, ln1g, ln1b, ln2g, ln2b,
        fw1, fb1, fw2, fb2, rw1, rb1, rw2, rb2, (float*)d_out, 3);
}

// Round 12
// 43.701 us; speedup vs baseline: 5.5235x; 5.5235x over previous
//
#include <hip/hip_runtime.h>
#include <math.h>
#include <type_traits>

#define DEV __device__ __forceinline__

DEV float gelu_exact(float x) {
    return 0.5f * x * (1.0f + erff(x * 0.70710678118654752f));
}

// ---------------- K1: adjacency -> CSR neighbor lists (R8, reps removed) ----
__global__ __launch_bounds__(512)
void mask_kernel(const float* __restrict__ emb,
                 unsigned short* __restrict__ nbr,
                 int* __restrict__ deg) {
    const int i = blockIdx.x;
    const int j = threadIdx.x;
    float ei[8], ej[8];
    float si = 0.f, sj = 0.f;
#pragma unroll
    for (int e = 0; e < 8; ++e) { ei[e] = emb[i * 8 + e]; si += ei[e] * ei[e]; }
    const int jj = (j < 500) ? j : 0;
#pragma unroll
    for (int e = 0; e < 8; ++e) { ej[e] = emb[jj * 8 + e]; sj += ej[e] * ej[e]; }
    const float ri = 1.0f / sqrtf(si);
    const float rj = 1.0f / sqrtf(sj);
    float dot = 0.f;
#pragma unroll
    for (int e = 0; e < 8; ++e) dot += (ei[e] * ri) * (ej[e] * rj);
    const bool pred = (j < 500) && (dot > 0.5f);
    const unsigned long long m = __ballot(pred);

    __shared__ unsigned wcnt[8];
    const int wave = j >> 6, lane = j & 63;
    if (lane == 0) wcnt[wave] = (unsigned)__popcll(m);
    __syncthreads();
    unsigned off = 0;
    for (int w = 0; w < wave; ++w) off += wcnt[w];
    if (pred) {
        const unsigned pos = off + (unsigned)__popcll(m & ((1ull << lane) - 1ull));
        if (pos < 128) nbr[i * 128 + pos] = (unsigned short)j;
    }
    if (j == 0) {
        unsigned t = 0;
        for (int w = 0; w < 8; ++w) t += wcnt[w];
        deg[i] = (int)(t > 128u ? 128u : t);
    }
}

// ---------------- K2/K3: restructured GAT ----------------
// grid = 96 graphs x 8 slices = 768 blocks (3/CU exact), 512 threads.
// Phase B: all 4 heads at once (no per-head duplication), h1 row stride
// HSTR=10/20 floats so b64/b128 reads spread over all bank groups
// ((5j+h) mod 8/16, 5 coprime). ssrc per-head stride 516 -> bank (4h+j)%32.
// Phase C: 2 threads per (head,row) item, each half the neighbor list,
// pair-combined via shfl_xor(1).
template <int C, int OUTS, bool PROJ, bool GELU_OUT>
__global__ __launch_bounds__(512)
void gat_kernel(const float* __restrict__ in,
                const float* __restrict__ pw,   // [3,8] (PROJ only)
                const float* __restrict__ pb,   // [8]
                const float* __restrict__ W,    // [8,4,C]
                const float* __restrict__ asrc, // [4,C]
                const float* __restrict__ adst, // [4,C]
                const float* __restrict__ bias, // [4*C]
                const unsigned short* __restrict__ nbr, // [500][128]
                const int* __restrict__ deg,            // [500]
                float* __restrict__ out) {      // [96,500,OUTS]
    using Vec = std::conditional_t<C == 2, float2, float4>;
    constexpr int HSTR = (C == 2) ? 10 : 20;
    const int b = blockIdx.x >> 3;
    const int slice = blockIdx.x & 7;
    const int tid = threadIdx.x;
    __shared__ float h1[500 * HSTR];    // 20000 / 40000 B
    __shared__ float ssrc[4 * 516];     // 8256 B

    // B: all-heads projection + src logits (global read direct, no staging)
    if (tid < 500) {
        float xv[8];
        if constexpr (PROJ) {
            const float* xr = in + ((size_t)b * 500 + tid) * 3;
            const float x0 = xr[0], x1 = xr[1], x2 = xr[2];
#pragma unroll
            for (int e = 0; e < 8; ++e)
                xv[e] = x0 * pw[e] + x1 * pw[8 + e] + x2 * pw[16 + e] + pb[e];
        } else {
            const float4* xr = (const float4*)(in + ((size_t)b * 500 + tid) * 8);
            const float4 v0 = xr[0], v1 = xr[1];
            xv[0] = v0.x; xv[1] = v0.y; xv[2] = v0.z; xv[3] = v0.w;
            xv[4] = v1.x; xv[5] = v1.y; xv[6] = v1.z; xv[7] = v1.w;
        }
#pragma unroll
        for (int h = 0; h < 4; ++h) {
            float acc[C];
#pragma unroll
            for (int c = 0; c < C; ++c) acc[c] = 0.f;
#pragma unroll
            for (int e = 0; e < 8; ++e) {
                const float xe = xv[e];
#pragma unroll
                for (int c = 0; c < C; ++c) acc[c] += xe * W[(e * 4 + h) * C + c];
            }
            float ss = 0.f;
            Vec hv;
#pragma unroll
            for (int c = 0; c < C; ++c) ss += acc[c] * asrc[h * C + c];
            if constexpr (C == 2) { hv.x = acc[0]; hv.y = acc[1]; }
            else { hv.x = acc[0]; hv.y = acc[1]; hv.z = acc[2]; hv.w = acc[3]; }
            *(Vec*)&h1[tid * HSTR + h * C] = hv;
            ssrc[h * 516 + tid] = ss;
        }
    }
    __syncthreads();

    // C: item = (head, row); 2 threads/item on neighbor-list halves
    const int pairId = tid >> 1;
    const int half = tid & 1;
    const int h = pairId & 3;
    const int local = pairId >> 2;          // 0..127
    const int i = slice * 63 + local;
    const bool valid = (local < 63) && (i < 500);
    float num[C];
#pragma unroll
    for (int c = 0; c < C; ++c) num[c] = 0.f;
    float den = 0.f;
    if (valid) {
        float dd = 0.f;
        {
            const Vec hi = *(const Vec*)&h1[i * HSTR + h * C];
            if constexpr (C == 2) dd = hi.x * adst[h * 2] + hi.y * adst[h * 2 + 1];
            else dd = hi.x * adst[h * 4] + hi.y * adst[h * 4 + 1] +
                      hi.z * adst[h * 4 + 2] + hi.w * adst[h * 4 + 3];
        }
        const int dg = deg[i];
        const int k0 = half ? (dg >> 1) : 0;
        const int k1 = half ? dg : (dg >> 1);
        const unsigned short* nb = nbr + i * 128;
        const float* sr = ssrc + h * 516;
        int k = k0;
        for (; k + 4 <= k1; k += 4) {
            const int j0 = nb[k], j1 = nb[k + 1], j2 = nb[k + 2], j3 = nb[k + 3];
            float e0 = dd + sr[j0]; e0 = (e0 > 0.f) ? e0 : 0.2f * e0;
            float e1 = dd + sr[j1]; e1 = (e1 > 0.f) ? e1 : 0.2f * e1;
            float e2 = dd + sr[j2]; e2 = (e2 > 0.f) ? e2 : 0.2f * e2;
            float e3 = dd + sr[j3]; e3 = (e3 > 0.f) ? e3 : 0.2f * e3;
            const float w0 = __expf(e0), w1 = __expf(e1);
            const float w2 = __expf(e2), w3 = __expf(e3);
            const Vec ha = *(const Vec*)&h1[j0 * HSTR + h * C];
            const Vec hb = *(const Vec*)&h1[j1 * HSTR + h * C];
            const Vec hc = *(const Vec*)&h1[j2 * HSTR + h * C];
            const Vec hd = *(const Vec*)&h1[j3 * HSTR + h * C];
            den += (w0 + w1) + (w2 + w3);
            if constexpr (C == 2) {
                num[0] += (w0 * ha.x + w1 * hb.x) + (w2 * hc.x + w3 * hd.x);
                num[1] += (w0 * ha.y + w1 * hb.y) + (w2 * hc.y + w3 * hd.y);
            } else {
                num[0] += (w0 * ha.x + w1 * hb.x) + (w2 * hc.x + w3 * hd.x);
                num[1] += (w0 * ha.y + w1 * hb.y) + (w2 * hc.y + w3 * hd.y);
                num[2] += (w0 * ha.z + w1 * hb.z) + (w2 * hc.z + w3 * hd.z);
                num[3] += (w0 * ha.w + w1 * hb.w) + (w2 * hc.w + w3 * hd.w);
            }
        }
        for (; k < k1; ++k) {
            const int j = nb[k];
            float e = dd + sr[j];
            e = (e > 0.f) ? e : 0.2f * e;
            const float w = __expf(e);
            den += w;
            const Vec hj = *(const Vec*)&h1[j * HSTR + h * C];
            if constexpr (C == 2) { num[0] += w * hj.x; num[1] += w * hj.y; }
            else { num[0] += w * hj.x; num[1] += w * hj.y;
                   num[2] += w * hj.z; num[3] += w * hj.w; }
        }
    }
    // combine the pair's halves (lanes 2t / 2t+1, same wave)
    den += __shfl_xor(den, 1);
#pragma unroll
    for (int c = 0; c < C; ++c) num[c] += __shfl_xor(num[c], 1);
    if (valid && half == 0) {
        const float inv = 1.0f / den;  // self-loop guarantees den > 0
        float* orow = out + ((size_t)b * 500 + i) * OUTS + h * C;
#pragma unroll
        for (int c = 0; c < C; ++c) {
            float v = num[c] * inv + bias[h * C + c];
            if constexpr (GELU_OUT) v = gelu_exact(v);
            orow[c] = v;
        }
    }
}

// ---------------- K4: transformer (R9 version, reps removed) ----------------
__global__ __launch_bounds__(64)
void transformer_kernel(const float* __restrict__ tin,  // [2000,24,16]
                        const float* __restrict__ wq, const float* __restrict__ bq,
                        const float* __restrict__ wk, const float* __restrict__ bk,
                        const float* __restrict__ wv, const float* __restrict__ bv,
                        const float* __restrict__ wo, const float* __restrict__ bo,
                        const float* __restrict__ ln1g, const float* __restrict__ ln1b,
                        const float* __restrict__ ln2g, const float* __restrict__ ln2b,
                        const float* __restrict__ fw1, const float* __restrict__ fb1,
                        const float* __restrict__ fw2, const float* __restrict__ fb2,
                        const float* __restrict__ rw1, const float* __restrict__ rb1,
                        const float* __restrict__ rw2, const float* __restrict__ rb2,
                        float* __restrict__ outp) {
    const int r = blockIdx.x;
    const int lane = threadIdx.x;
    const int d = lane & 15;
    const int srow = lane >> 4;
    const int f = lane & 31;
    const int s2 = lane >> 5;
    __shared__ float t0[24][16], qs[24][16], ks[24][16], vs[24][16];
    __shared__ float os[24][16], t1[24][16], hid[24][32], pooled[16];

    const float4* row4 = (const float4*)(tin + (size_t)r * 384);
    float4* t04 = (float4*)&t0[0][0];
#pragma unroll 1
    for (int idx = lane; idx < 96; idx += 64) t04[idx] = row4[idx];
    float wqc[16], wkc[16], wvc[16];
#pragma unroll
    for (int e = 0; e < 16; ++e) {
        wqc[e] = wq[e * 16 + d];
        wkc[e] = wk[e * 16 + d];
        wvc[e] = wv[e * 16 + d];
    }
    const float bqv = bq[d], bkv = bk[d], bvv = bv[d];
    __syncthreads();

#pragma unroll 1
    for (int it = 0; it < 6; ++it) {
        const int s = it * 4 + srow;
        const float4 r0 = *(const float4*)&t0[s][0];
        const float4 r1 = *(const float4*)&t0[s][4];
        const float4 r2 = *(const float4*)&t0[s][8];
        const float4 r3 = *(const float4*)&t0[s][12];
        const float te[16] = {r0.x, r0.y, r0.z, r0.w, r1.x, r1.y, r1.z, r1.w,
                              r2.x, r2.y, r2.z, r2.w, r3.x, r3.y, r3.z, r3.w};
        float aq = bqv, ak = bkv, av = bvv;
#pragma unroll
        for (int e = 0; e < 16; ++e) {
            aq += te[e] * wqc[e];
            ak += te[e] * wkc[e];
            av += te[e] * wvc[e];
        }
        qs[s][d] = aq; ks[s][d] = ak; vs[s][d] = av;
    }
    __syncthreads();

    if (lane < 48) {
        const int h = lane / 24, s = lane % 24;
        const float4 q0 = *(const float4*)&qs[s][h * 8];
        const float4 q1 = *(const float4*)&qs[s][h * 8 + 4];
        float sc[24];
        float mx = -1e30f;
#pragma unroll
        for (int t = 0; t < 24; ++t) {
            const float4 k0 = *(const float4*)&ks[t][h * 8];
            const float4 k1 = *(const float4*)&ks[t][h * 8 + 4];
            float a = q0.x * k0.x + q0.y * k0.y + q0.z * k0.z + q0.w * k0.w +
                      q1.x * k1.x + q1.y * k1.y + q1.z * k1.z + q1.w * k1.w;
            a *= 0.35355339059327373f;
            sc[t] = a;
            mx = fmaxf(mx, a);
        }
        float sum = 0.f;
#pragma unroll
        for (int t = 0; t < 24; ++t) { sc[t] = __expf(sc[t] - mx); sum += sc[t]; }
        const float inv = 1.0f / sum;
        float o0x = 0.f, o0y = 0.f, o0z = 0.f, o0w = 0.f;
        float o1x = 0.f, o1y = 0.f, o1z = 0.f, o1w = 0.f;
#pragma unroll
        for (int t = 0; t < 24; ++t) {
            const float4 v0 = *(const float4*)&vs[t][h * 8];
            const float4 v1 = *(const float4*)&vs[t][h * 8 + 4];
            const float w = sc[t];
            o0x += w * v0.x; o0y += w * v0.y; o0z += w * v0.z; o0w += w * v0.w;
            o1x += w * v1.x; o1y += w * v1.y; o1z += w * v1.z; o1w += w * v1.w;
        }
        float4 ov0 = {o0x * inv, o0y * inv, o0z * inv, o0w * inv};
        float4 ov1 = {o1x * inv, o1y * inv, o1z * inv, o1w * inv};
        *(float4*)&os[s][h * 8] = ov0;
        *(float4*)&os[s][h * 8 + 4] = ov1;
    }
    float woc[16];
#pragma unroll
    for (int hd = 0; hd < 16; ++hd) woc[hd] = wo[hd * 16 + d];
    const float bov = bo[d];
    const float g1v = ln1g[d], be1v = ln1b[d];
    __syncthreads();

#pragma unroll 1
    for (int it = 0; it < 6; ++it) {
        const int s = it * 4 + srow;
        const float4 r0 = *(const float4*)&os[s][0];
        const float4 r1 = *(const float4*)&os[s][4];
        const float4 r2 = *(const float4*)&os[s][8];
        const float4 r3 = *(const float4*)&os[s][12];
        const float oe[16] = {r0.x, r0.y, r0.z, r0.w, r1.x, r1.y, r1.z, r1.w,
                              r2.x, r2.y, r2.z, r2.w, r3.x, r3.y, r3.z, r3.w};
        float a = bov;
#pragma unroll
        for (int hd = 0; hd < 16; ++hd) a += oe[hd] * woc[hd];
        const float xv = t0[s][d] + a;
        float s1 = xv, sq = xv * xv;
        s1 += __shfl_xor(s1, 1); sq += __shfl_xor(sq, 1);
        s1 += __shfl_xor(s1, 2); sq += __shfl_xor(sq, 2);
        s1 += __shfl_xor(s1, 4); sq += __shfl_xor(sq, 4);
        s1 += __shfl_xor(s1, 8); sq += __shfl_xor(sq, 8);
        const float mean = s1 * 0.0625f;
        const float var = fmaxf(sq * 0.0625f - mean * mean, 0.f);
        t1[s][d] = (xv - mean) * rsqrtf(var + 1e-3f) * g1v + be1v;
    }
    float f1c[16];
#pragma unroll
    for (int e = 0; e < 16; ++e) f1c[e] = fw1[e * 32 + f];
    const float fb1v = fb1[f];
    __syncthreads();

#pragma unroll 1
    for (int it = 0; it < 12; ++it) {
        const int s = it * 2 + s2;
        const float4 r0 = *(const float4*)&t1[s][0];
        const float4 r1 = *(const float4*)&t1[s][4];
        const float4 r2 = *(const float4*)&t1[s][8];
        const float4 r3 = *(const float4*)&t1[s][12];
        const float te[16] = {r0.x, r0.y, r0.z, r0.w, r1.x, r1.y, r1.z, r1.w,
                              r2.x, r2.y, r2.z, r2.w, r3.x, r3.y, r3.z, r3.w};
        float a = fb1v;
#pragma unroll
        for (int e = 0; e < 16; ++e) a += te[e] * f1c[e];
        hid[s][f] = gelu_exact(a);
    }
    float f2c[32];
#pragma unroll
    for (int ff = 0; ff < 32; ++ff) f2c[ff] = fw2[ff * 16 + d];
    const float fb2v = fb2[d];
    const float g2v = ln2g[d], be2v = ln2b[d];
    __syncthreads();

    float pacc = 0.f;
#pragma unroll 1
    for (int it = 0; it < 6; ++it) {
        const int s = it * 4 + srow;
        float he[32];
#pragma unroll
        for (int q8 = 0; q8 < 8; ++q8) {
            const float4 rv = *(const float4*)&hid[s][q8 * 4];
            he[q8 * 4 + 0] = rv.x; he[q8 * 4 + 1] = rv.y;
            he[q8 * 4 + 2] = rv.z; he[q8 * 4 + 3] = rv.w;
        }
        float a = fb2v;
#pragma unroll
        for (int ff = 0; ff < 32; ++ff) a += he[ff] * f2c[ff];
        const float xv = t1[s][d] + a;
        float s1 = xv, sq = xv * xv;
        s1 += __shfl_xor(s1, 1); sq += __shfl_xor(sq, 1);
        s1 += __shfl_xor(s1, 2); sq += __shfl_xor(sq, 2);
        s1 += __shfl_xor(s1, 4); sq += __shfl_xor(sq, 4);
        s1 += __shfl_xor(s1, 8); sq += __shfl_xor(sq, 8);
        const float mean = s1 * 0.0625f;
        const float var = fmaxf(sq * 0.0625f - mean * mean, 0.f);
        pacc += (xv - mean) * rsqrtf(var + 1e-3f) * g2v + be2v;
    }
    pacc += __shfl_xor(pacc, 16);
    pacc += __shfl_xor(pacc, 32);
    if (lane < 16) pooled[lane] = pacc * (1.0f / 24.0f);
    __syncthreads();

    float partial = 0.f;
    if (lane < 16) {
        float a = rb1[lane];
#pragma unroll
        for (int e = 0; e < 16; ++e) a += pooled[e] * rw1[e * 16 + lane];
        partial = gelu_exact(a) * rw2[lane];
    }
    partial += __shfl_xor(partial, 8);
    partial += __shfl_xor(partial, 4);
    partial += __shfl_xor(partial, 2);
    partial += __shfl_xor(partial, 1);
    if (lane == 0) outp[r] = partial + rb2[0];
}

extern "C" void kernel_launch(void* const* d_in, const int* in_sizes, int n_in,
                              void* d_out, int out_size, void* d_ws, size_t ws_size,
                              hipStream_t stream) {
    const float* x      = (const float*)d_in[0];
    const float* emb    = (const float*)d_in[1];
    const float* proj_w = (const float*)d_in[2];
    const float* proj_b = (const float*)d_in[3];
    const float* g1_w   = (const float*)d_in[4];
    const float* g1_as  = (const float*)d_in[5];
    const float* g1_ad  = (const float*)d_in[6];
    const float* g1_b   = (const float*)d_in[7];
    const float* g2_w   = (const float*)d_in[8];
    const float* g2_as  = (const float*)d_in[9];
    const float* g2_ad  = (const float*)d_in[10];
    const float* g2_b   = (const float*)d_in[11];
    const float* wq = (const float*)d_in[12];
    const float* bq = (const float*)d_in[13];
    const float* wk = (const float*)d_in[14];
    const float* bk = (const float*)d_in[15];
    const float* wv = (const float*)d_in[16];
    const float* bv = (const float*)d_in[17];
    const float* wo = (const float*)d_in[18];
    const float* bo = (const float*)d_in[19];
    const float* ln1g = (const float*)d_in[20];
    const float* ln1b = (const float*)d_in[21];
    const float* ln2g = (const float*)d_in[22];
    const float* ln2b = (const float*)d_in[23];
    const float* fw1 = (const float*)d_in[24];
    const float* fb1 = (const float*)d_in[25];
    const float* fw2 = (const float*)d_in[26];
    const float* fb2 = (const float*)d_in[27];
    const float* rw1 = (const float*)d_in[28];
    const float* rb1 = (const float*)d_in[29];
    const float* rw2 = (const float*)d_in[30];
    const float* rb2 = (const float*)d_in[31];

    unsigned short* nbr = (unsigned short*)d_ws;                  // 128,000 B (pad 131072)
    int* deg   = (int*)((char*)d_ws + 131072);                    // 2,000 B (pad 4096)
    float* h_g1  = (float*)((char*)d_ws + 135168);                // 1,536,000 B
    float* t_buf = (float*)((char*)d_ws + 135168 + 1536000);      // 3,072,000 B

    mask_kernel<<<500, 512, 0, stream>>>(emb, nbr, deg);
    gat_kernel<2, 8, true, true><<<768, 512, 0, stream>>>(
        x, proj_w, proj_b, g1_w, g1_as, g1_ad, g1_b, nbr, deg, h_g1);
    gat_kernel<4, 16, false, false><<<768, 512, 0, stream>>>(
        h_g1, nullptr, nullptr, g2_w, g2_as, g2_ad, g2_b, nbr, deg, t_buf);
    transformer_kernel<<<2000, 64, 0, stream>>>(
        t_buf, wq, bq, wk, bk, wv, bv, wo, bo, ln1g, ln1b, ln2g, ln2b,
        fw1, fb1, fw2, fb2, rw1, rb1, rw2, rb2, (float*)d_out);
}